// Round 2
// baseline (1442.066 us; speedup 1.0000x reference)
//
#include <hip/hip_runtime.h>
#include <cstdint>
#include <cstddef>

#define BTOT 4096
#define TDIM 16
#define KDIM 2048
#define DIM  256
#define BM   32
#define KC   32

typedef const __attribute__((address_space(1))) unsigned int ga_u32;
typedef __attribute__((address_space(3))) unsigned int ls_u32;

__device__ __forceinline__ void gll16(const float* g, float* l) {
  __builtin_amdgcn_global_load_lds((ga_u32*)g, (ls_u32*)l, 16, 0, 0);
}

__device__ __forceinline__ void fma4(float4& a, float s, const float4 w) {
  a.x = fmaf(s, w.x, a.x);
  a.y = fmaf(s, w.y, a.y);
  a.z = fmaf(s, w.z, a.z);
  a.w = fmaf(s, w.w, a.w);
}

// ---------------- kernel 1: transpose Wp/We -> WpT/WeT ----------------
// Wp: [DIM=256][KDIM=2048] row-major -> WpT: [KDIM][DIM]
__global__ __launch_bounds__(256) void transpose_k(
    const float* __restrict__ Wp, const float* __restrict__ We,
    float* __restrict__ WpT, float* __restrict__ WeT)
{
  __shared__ float tile[32][33];
  const int mat = blockIdx.y;
  const float* src = mat ? We : Wp;
  float* dst = mat ? WeT : WpT;
  const int ct = blockIdx.x >> 6;   // 0..7   c-tile
  const int kt = blockIdx.x & 63;   // 0..63  k-tile
  const int tx = threadIdx.x & 31;
  const int ty = threadIdx.x >> 5;  // 0..7
#pragma unroll
  for (int i = 0; i < 4; ++i) {
    const int row = ty + i * 8;     // c within tile
    tile[row][tx] = src[(size_t)(ct * 32 + row) * KDIM + kt * 32 + tx];
  }
  __syncthreads();
#pragma unroll
  for (int i = 0; i < 4; ++i) {
    const int row = ty + i * 8;     // k within tile
    dst[(size_t)(kt * 32 + row) * DIM + ct * 32 + tx] = tile[tx][row];
  }
}

// ---------------- kernel 2: fused mean-pool + projection GEMM ----------------
// grid = (BTOT/BM) * ksplit blocks, 256 threads.
// Writes partial sums part[sp][b][c]; reduced in transform_k.
// Block order bt*ksplit+sp: same-sp blocks are 8 apart -> under round-robin
// XCD dispatch each XCD sees one 0.5 MiB W-slice (L2-resident).
__global__ __launch_bounds__(256) void pool_gemm_k(
    const float* __restrict__ pre, const float* __restrict__ eff,
    const float* __restrict__ WpT, const float* __restrict__ WeT,
    float* __restrict__ partP, float* __restrict__ partE,
    int kshift)
{
  __shared__ float s_wT[KC][DIM];    // 32 KiB, reused for Wp then We each chunk
  __shared__ float s_avP[KC][BM];    // 4 KiB, transposed avg tile [k][b]
  __shared__ float s_avE[KC][BM];    // 4 KiB

  const int tid = threadIdx.x;
  const int ksplit = 1 << kshift;
  const int bt = blockIdx.x >> kshift;
  const int sp = blockIdx.x & (ksplit - 1);
  const int b0 = bt * BM;
  const int krange = KDIM >> kshift;
  const int k0 = sp * krange;
  const int nchunk = krange / KC;

  const int b_l = tid >> 3;          // 0..31 pooled sample
  const int kq  = tid & 7;           // 0..7  k-quad within chunk
  const int wv  = tid >> 6;          // wave id 0..3 -> row group
  const int lane = tid & 63;
  const int cg4 = lane * 4;          // col base (contiguous per lane)
  const int rg8 = wv * 8;            // row base

  float4 accP[8], accE[8];
#pragma unroll
  for (int i = 0; i < 8; ++i) {
    accP[i] = make_float4(0.f, 0.f, 0.f, 0.f);
    accE[i] = make_float4(0.f, 0.f, 0.f, 0.f);
  }

  const size_t rowBase = (size_t)(b0 + b_l) * TDIM * KDIM;
  const float sc = 1.0f / TDIM;

  for (int c = 0; c < nchunk; ++c) {
    const int kc = k0 + c * KC;

    // ---------- phase P: stage WpT chunk + pool pre ----------
#pragma unroll
    for (int r = 0; r < 8; ++r) {
      const int kk = rg8 + r;
      gll16(&WpT[(size_t)(kc + kk) * DIM + cg4], &s_wT[kk][0]);
    }
    {
      const float* gp = pre + rowBase + kc + kq * 4;
      float4 a = make_float4(0.f, 0.f, 0.f, 0.f);
#pragma unroll
      for (int t = 0; t < TDIM; ++t) {
        const float4 v = *(const float4*)(gp + (size_t)t * KDIM);
        a.x += v.x; a.y += v.y; a.z += v.z; a.w += v.w;
      }
      s_avP[kq * 4 + 0][b_l] = a.x * sc;
      s_avP[kq * 4 + 1][b_l] = a.y * sc;
      s_avP[kq * 4 + 2][b_l] = a.z * sc;
      s_avP[kq * 4 + 3][b_l] = a.w * sc;
    }
    __syncthreads();
#pragma unroll 8
    for (int kk = 0; kk < KC; ++kk) {
      const float4 w  = *(const float4*)&s_wT[kk][cg4];
      const float4 a0 = *(const float4*)&s_avP[kk][rg8];
      const float4 a1 = *(const float4*)&s_avP[kk][rg8 + 4];
      fma4(accP[0], a0.x, w); fma4(accP[1], a0.y, w);
      fma4(accP[2], a0.z, w); fma4(accP[3], a0.w, w);
      fma4(accP[4], a1.x, w); fma4(accP[5], a1.y, w);
      fma4(accP[6], a1.z, w); fma4(accP[7], a1.w, w);
    }
    __syncthreads();

    // ---------- phase E: stage WeT chunk + pool eff ----------
#pragma unroll
    for (int r = 0; r < 8; ++r) {
      const int kk = rg8 + r;
      gll16(&WeT[(size_t)(kc + kk) * DIM + cg4], &s_wT[kk][0]);
    }
    {
      const float* ge = eff + rowBase + kc + kq * 4;
      float4 a = make_float4(0.f, 0.f, 0.f, 0.f);
#pragma unroll
      for (int t = 0; t < TDIM; ++t) {
        const float4 v = *(const float4*)(ge + (size_t)t * KDIM);
        a.x += v.x; a.y += v.y; a.z += v.z; a.w += v.w;
      }
      s_avE[kq * 4 + 0][b_l] = a.x * sc;
      s_avE[kq * 4 + 1][b_l] = a.y * sc;
      s_avE[kq * 4 + 2][b_l] = a.z * sc;
      s_avE[kq * 4 + 3][b_l] = a.w * sc;
    }
    __syncthreads();
#pragma unroll 8
    for (int kk = 0; kk < KC; ++kk) {
      const float4 w  = *(const float4*)&s_wT[kk][cg4];
      const float4 a0 = *(const float4*)&s_avE[kk][rg8];
      const float4 a1 = *(const float4*)&s_avE[kk][rg8 + 4];
      fma4(accE[0], a0.x, w); fma4(accE[1], a0.y, w);
      fma4(accE[2], a0.z, w); fma4(accE[3], a0.w, w);
      fma4(accE[4], a1.x, w); fma4(accE[5], a1.y, w);
      fma4(accE[6], a1.z, w); fma4(accE[7], a1.w, w);
    }
    __syncthreads();
  }

  // store partials: part[sp][b0+rg8+i][cg4..cg4+3]
  const size_t obase = ((size_t)sp * BTOT + b0 + rg8) * DIM + cg4;
#pragma unroll
  for (int i = 0; i < 8; ++i) {
    *(float4*)&partP[obase + (size_t)i * DIM] = accP[i];
    *(float4*)&partE[obase + (size_t)i * DIM] = accE[i];
  }
}

// ---------------- kernel 3: reduce partials + bias, gather transform ----------------
__global__ __launch_bounds__(256) void transform_k(
    const float* __restrict__ partP, const float* __restrict__ partE,
    const int* __restrict__ action,
    const float* __restrict__ bpv, const float* __restrict__ bev,
    const float* __restrict__ Wt,
    float* __restrict__ outP, float* __restrict__ outE,
    int ksplit)
{
  __shared__ float p_lds[DIM];
  const int b = blockIdx.x;
  const int tid = threadIdx.x;

  float pv = bpv[tid];
  float ev = bev[tid];
  for (int s = 0; s < ksplit; ++s) {
    pv += partP[((size_t)s * BTOT + b) * DIM + tid];
    ev += partE[((size_t)s * BTOT + b) * DIM + tid];
  }
  p_lds[tid] = pv;
  outE[(size_t)b * DIM + tid] = ev;
  __syncthreads();

  const int a = action[b];
  const float* Wb = Wt + (size_t)a * DIM * DIM;
  const int wv = tid >> 6, lane = tid & 63;
  const int r = lane >> 4, jp = lane & 15;

  float4 p4[4];
#pragma unroll
  for (int q = 0; q < 4; ++q) p4[q] = *(const float4*)&p_lds[jp * 16 + q * 4];

#pragma unroll 4
  for (int it = 0; it < 16; ++it) {
    const int row = wv * 64 + it * 4 + r;
    const float* wr = Wb + (size_t)row * DIM + jp * 16;
    float acc = 0.f;
#pragma unroll
    for (int q = 0; q < 4; ++q) {
      const float4 w4 = *(const float4*)(wr + q * 4);
      acc = fmaf(w4.x, p4[q].x, acc);
      acc = fmaf(w4.y, p4[q].y, acc);
      acc = fmaf(w4.z, p4[q].z, acc);
      acc = fmaf(w4.w, p4[q].w, acc);
    }
    acc += __shfl_xor(acc, 1);
    acc += __shfl_xor(acc, 2);
    acc += __shfl_xor(acc, 4);
    acc += __shfl_xor(acc, 8);
    if (jp == 0) outP[(size_t)b * DIM + row] = acc;
  }
}

extern "C" void kernel_launch(void* const* d_in, const int* in_sizes, int n_in,
                              void* d_out, int out_size, void* d_ws, size_t ws_size,
                              hipStream_t stream) {
  const float* pre    = (const float*)d_in[0];
  const float* eff    = (const float*)d_in[1];
  const int*   action = (const int*)d_in[2];
  const float* Wp     = (const float*)d_in[3];
  const float* bp     = (const float*)d_in[4];
  const float* We     = (const float*)d_in[5];
  const float* be     = (const float*)d_in[6];
  const float* Wt     = (const float*)d_in[7];

  float* outP = (float*)d_out;
  float* outE = outP + (size_t)BTOT * DIM;

  const size_t fl = ws_size / sizeof(float);
  const size_t M  = (size_t)BTOT * DIM;       // 1,048,576 floats per partial slab
  const size_t TR = 2 * (size_t)KDIM * DIM;   // both transposed weights

  int kshift; int use_ws = 1;
  if      (fl >= 16 * M + TR) kshift = 3;
  else if (fl >=  8 * M + TR) kshift = 2;
  else if (fl >=  4 * M + TR) kshift = 1;
  else if (fl >=  2 * M + TR) kshift = 0;
  else { kshift = 0; use_ws = 0; }
  const int ksplit = 1 << kshift;

  float* wsf = (float*)d_ws;
  float *WpT, *WeT, *partP, *partE;
  if (use_ws) {
    partP = wsf;
    partE = wsf + (size_t)ksplit * M;
    WpT   = wsf + 2 * (size_t)ksplit * M;
    WeT   = WpT + (size_t)KDIM * DIM;
  } else {
    // minimal-ws fallback: partials alias the output buffer (ksplit==1);
    // transform_k reads its block's slice before overwriting it.
    partP = outP;
    partE = outE;
    WpT   = wsf;
    WeT   = WpT + (size_t)KDIM * DIM;
  }

  hipLaunchKernelGGL(transpose_k, dim3(512, 2), dim3(256), 0, stream,
                     Wp, We, WpT, WeT);
  hipLaunchKernelGGL(pool_gemm_k, dim3((BTOT / BM) * ksplit), dim3(256), 0, stream,
                     pre, eff, WpT, WeT, partP, partE, kshift);
  hipLaunchKernelGGL(transform_k, dim3(BTOT), dim3(256), 0, stream,
                     partP, partE, action, bp, be, Wt, outP, outE, ksplit);
}